// Round 2
// baseline (405.892 us; speedup 1.0000x reference)
//
#include <hip/hip_runtime.h>
#include <math.h>

#define BS 32
#define Q  600
#define NC 152
#define T  32
#define MT (BS*T)                   // 1024 targets total
#define CM_SIZE ((size_t)BS*Q*MT)   // 19660800 elements per cost matrix
#define NSLOT 10                    // ceil(600/64)
#define FBIG 1e30f
#define NPROB 64                    // 2 matrices x 32 batches
#define LSA_BLOCKS 64

typedef float vfloat4 __attribute__((ext_vector_type(4)));  // clang-native for nt-store

// ---------------------------------------------------------------------------
// Shared eval helpers (identical arithmetic order to the verified kernel so
// cost-matrix values and LSA-block values stay bitwise consistent).
// ---------------------------------------------------------------------------
__device__ __forceinline__ float pair_cost(const float4 ob, const float4 tb, const float cc) {
    const float ocx = ob.x, ocy = ob.y, ow = ob.z, oh = ob.w;
    const float ox1 = ocx - 0.5f*ow, oy1 = ocy - 0.5f*oh;
    const float ox2 = ocx + 0.5f*ow, oy2 = ocy + 0.5f*oh;
    const float area1 = ow * oh;

    const float cb = fabsf(ocx-tb.x) + fabsf(ocy-tb.y)
                   + fabsf(ow -tb.z) + fabsf(oh -tb.w);

    const float tx1 = fmaf(-0.5f, tb.z, tb.x), ty1 = fmaf(-0.5f, tb.w, tb.y);
    const float tx2 = fmaf( 0.5f, tb.z, tb.x), ty2 = fmaf( 0.5f, tb.w, tb.y);
    const float area2 = tb.z * tb.w;

    const float ltx = fmaxf(ox1,tx1), lty = fmaxf(oy1,ty1);
    const float rbx = fminf(ox2,tx2), rby = fminf(oy2,ty2);
    const float iw = fmaxf(rbx-ltx, 0.0f), ih = fmaxf(rby-lty, 0.0f);
    const float inter = iw*ih;
    const float uni = area1 + area2 - inter;

    const float cx1 = fminf(ox1,tx1), cy1 = fminf(oy1,ty1);
    const float cx2 = fmaxf(ox2,tx2), cy2 = fmaxf(oy2,ty2);
    const float areac = (cx2-cx1)*(cy2-cy1);

    const float giou = inter * __builtin_amdgcn_rcpf(uni)
                     - (areac - uni) * __builtin_amdgcn_rcpf(areac);
    return cb + cc - giou;
}

// wave-wide softmax of one 152-class row into sp[0..151]
__device__ __forceinline__ void softmax_row(const float* __restrict__ lrow,
                                            const int lane, float* sp) {
    const float l0 = (lane       < NC) ? lrow[lane]       : -INFINITY;
    const float l1 = (lane + 64  < NC) ? lrow[lane + 64]  : -INFINITY;
    const float l2 = (lane + 128 < NC) ? lrow[lane + 128] : -INFINITY;
    float m = fmaxf(l0, fmaxf(l1, l2));
    #pragma unroll
    for (int off = 32; off > 0; off >>= 1) m = fmaxf(m, __shfl_xor(m, off));
    const float e0 = expf(l0 - m), e1 = expf(l1 - m), e2 = expf(l2 - m);
    float s = e0 + e1 + e2;
    #pragma unroll
    for (int off = 32; off > 0; off >>= 1) s += __shfl_xor(s, off);
    const float inv = 1.0f / s;
    if (lane       < NC) sp[lane]       = e0 * inv;
    if (lane + 64  < NC) sp[lane + 64]  = e1 * inv;
    if (lane + 128 < NC) sp[lane + 128] = e2 * inv;
}

__device__ __forceinline__ unsigned f32_sortable(float f) {
  unsigned u = __float_as_uint(f);
  return u ^ ((unsigned)((int)u >> 31) | 0x80000000u);
}
__device__ __forceinline__ float f32_unsortable(unsigned s) {
  unsigned m = (unsigned)((int)(~s) >> 31) | 0x80000000u;
  return __uint_as_float(s ^ m);
}

// u32 DPP wave-min, result broadcast via readlane 63 (VALU pipe only)
__device__ __forceinline__ unsigned wave_min_u32(unsigned x) {
  int v = (int)x;
  #define ST(CTRL, RMASK) { \
    int p = __builtin_amdgcn_update_dpp(v, v, CTRL, RMASK, 0xF, false); \
    v = ((unsigned)p < (unsigned)v) ? p : v; }
  ST(0xB1, 0xF)   // quad_perm [1,0,3,2]  : xor 1
  ST(0x4E, 0xF)   // quad_perm [2,3,0,1]  : xor 2
  ST(0x141, 0xF)  // row_half_mirror      : xor 4
  ST(0x140, 0xF)  // row_mirror           : xor 8
  ST(0x142, 0xA)  // row_bcast15 -> rows 1,3
  ST(0x143, 0xC)  // row_bcast31 -> rows 2,3
  #undef ST
  return (unsigned)__builtin_amdgcn_readlane(v, 63);
}

// u64-key DPP wave-min (kept for the fallback kernel)
__device__ __forceinline__ unsigned long long wave_min_u64(unsigned long long k) {
  #define STAGE(CTRL, RMASK) { \
    int lo = (int)(unsigned)(k & 0xffffffffull); \
    int hi = (int)(unsigned)(k >> 32); \
    int plo = __builtin_amdgcn_update_dpp(lo, lo, CTRL, RMASK, 0xF, false); \
    int phi = __builtin_amdgcn_update_dpp(hi, hi, CTRL, RMASK, 0xF, false); \
    unsigned long long p = ((unsigned long long)(unsigned)phi << 32) | (unsigned)plo; \
    k = (p < k) ? p : k; }
  STAGE(0xB1, 0xF) STAGE(0x4E, 0xF) STAGE(0x141, 0xF)
  STAGE(0x140, 0xF) STAGE(0x142, 0xA) STAGE(0x143, 0xC)
  #undef STAGE
  unsigned lo63 = (unsigned)__builtin_amdgcn_readlane((int)(unsigned)(k & 0xffffffffull), 63);
  unsigned hi63 = (unsigned)__builtin_amdgcn_readlane((int)(unsigned)(k >> 32), 63);
  return ((unsigned long long)hi63 << 32) | lo63;
}

// ---------------------------------------------------------------------------
// FUSED kernel. blockIdx 0..63   : LSA blocks (self-compute cost block into
//                                  private global scratch, then 1-wave JV).
//               blockIdx 64..9663: cost-matrix blocks (one WAVE per row).
// No cross-block communication of any kind.
// ---------------------------------------------------------------------------
__global__ __launch_bounds__(256, 4) void fused_kernel(
    const float* __restrict__ logits_s, const float* __restrict__ logits_o,
    const float* __restrict__ boxes_s,  const float* __restrict__ boxes_o,
    const float* __restrict__ tbb_s,    const float* __restrict__ tbb_o,
    const int*   __restrict__ tids_s,   const int*   __restrict__ tids_o,
    float* __restrict__ C_s, float* __restrict__ C_o,
    float* __restrict__ scratch, float* __restrict__ idx_out)
{
    const int tid = threadIdx.x, w = tid >> 6, lane = tid & 63;

    __shared__ float  sprob[4][NC];
    __shared__ float  u_s[T + 1];
    __shared__ int    p_s[Q + 1];
    __shared__ float4 tb_sh[T];
    __shared__ int    cls_sh[T];

    if (blockIdx.x >= LSA_BLOCKS) {
        // =============== cost-matrix path (one wave per row) ===============
        const int rowg = (blockIdx.x - LSA_BLOCKS) * 4 + w;   // 0..38399
        const int mat = rowg / (BS * Q);
        const int r   = rowg % (BS * Q);

        const float* logits = mat ? logits_o : logits_s;
        const float* boxes  = mat ? boxes_o  : boxes_s;
        const float* tbb    = mat ? tbb_o    : tbb_s;
        const int*   tids   = mat ? tids_o   : tids_s;
        float* C = mat ? C_o : C_s;

        softmax_row(logits + (size_t)r * NC, lane, sprob[w]);  // per-wave buffer

        const float4 ob = ((const float4*)boxes)[r];
        float* Crow = C + (size_t)r * MT;

        #pragma unroll
        for (int it = 0; it < 4; ++it) {
            const int t0 = it*256 + lane*4;
            const int4 cls4 = ((const int4*)tids)[t0 >> 2];
            vfloat4 res;
            #pragma unroll
            for (int k = 0; k < 4; ++k) {
                const int t = t0 + k;
                const float cc = -sprob[w][(&cls4.x)[k]];
                const float4 tb = ((const float4*)tbb)[t];
                res[k] = pair_cost(ob, tb, cc);
            }
            __builtin_nontemporal_store(res, (vfloat4*)(Crow + t0));
        }
        return;
    }

    // ======================= LSA path ==================================
    const int prob = blockIdx.x;          // 0..63
    const int mat = prob >> 5, b = prob & 31;
    const float* logits = mat ? logits_o : logits_s;
    const float* boxes  = mat ? boxes_o  : boxes_s;
    const float* tbb    = mat ? tbb_o    : tbb_s;
    const int*   tids   = mat ? tids_o   : tids_s;
    float* blk = scratch + (size_t)prob * T * Q;     // private [T][Q] slab

    if (tid < T) {
        tb_sh[tid]  = ((const float4*)tbb)[b*T + tid];
        cls_sh[tid] = tids[b*T + tid];
    }
    for (int j = tid; j <= Q; j += 256) p_s[j] = 0;
    if (tid <= T) u_s[tid] = 0.0f;
    __syncthreads();

    // ---- self-stage the 32x600 cost block (4 waves, 150 rows each) ----
    for (int q = w; q < Q; q += 4) {
        const int r = b*Q + q;
        softmax_row(logits + (size_t)r * NC, lane, sprob[w]);
        const float4 ob = ((const float4*)boxes)[r];
        if (lane < T) {
            const float cc = -sprob[w][cls_sh[lane]];
            blk[(size_t)lane * Q + q] = pair_cost(ob, tb_sh[lane], cc);
        }
    }
    __syncthreads();
    if (w != 0) return;                    // waves 1..3 done; wave 0 runs JV

    __builtin_amdgcn_s_setprio(3);         // keep the serial chain fed

    float vreg[NSLOT], minv[NSLOT];
    int   wayreg[NSLOT], low[NSLOT];
    #pragma unroll
    for (int c = 0; c < NSLOT; ++c) vreg[c] = 0.0f;

    for (int i = 1; i <= T; ++i) {
        #pragma unroll
        for (int c = 0; c < NSLOT; ++c) {
            const int q0 = c*64 + lane;
            minv[c] = FBIG;
            wayreg[c] = 0;
            low[c] = (q0 < Q) ? (((q0 + 1) << 6) | p_s[q0 + 1]) : 0x3FFFFF;
        }
        unsigned usedmask = 0;
        float Dcum = 0.0f;
        int j0 = 0, i0 = i, jfin;

        while (true) {
            const float u0 = u_s[i0];
            const float* crow = blk + (size_t)(i0 - 1) * Q;

            float cst[NSLOT];
            #pragma unroll
            for (int c = 0; c < NSLOT; ++c) {
                const int q0 = c*64 + lane;
                cst[c] = (q0 < Q) ? crow[q0] : FBIG;
            }
            const float sh = Dcum - u0;

            float bm[NSLOT];
            #pragma unroll
            for (int c = 0; c < NSLOT; ++c) {
                const bool fre = !((usedmask >> c) & 1u);
                const float cur = (cst[c] - vreg[c]) + sh;   // keep verified op order
                const bool upd = fre && (cur < minv[c]);
                wayreg[c] = upd ? j0 : wayreg[c];
                minv[c]   = upd ? cur : minv[c];
                bm[c] = fre ? minv[c] : FBIG;
            }
            // per-lane f32 min tree (v_min3-friendly groupings)
            const float m0 = fminf(bm[0], fminf(bm[1], bm[2]));
            const float m1 = fminf(bm[3], fminf(bm[4], bm[5]));
            const float m2 = fminf(bm[6], fminf(bm[7], bm[8]));
            const float best = fminf(fminf(m0, m1), fminf(m2, bm[9]));
            // smallest slot index holding best (matches old low-ordering)
            int blow = 0x3FFFFF;
            #pragma unroll
            for (int c = NSLOT - 1; c >= 0; --c) blow = (bm[c] == best) ? low[c] : blow;

            const unsigned sb = f32_sortable(best);
            const unsigned gb = wave_min_u32(sb);
            const unsigned long long mask = __ballot(sb == gb);
            const int src = __ffsll(mask) - 1;
            const int blow_w = __builtin_amdgcn_readlane(blow, src);

            Dcum = f32_unsortable(gb);
            const int j1  = (blow_w >> 6) & 0x3FF;
            const int pj1 = blow_w & 0x3F;

            if (pj1 == 0) { jfin = j1; break; }
            const int owner1 = (j1 - 1) & 63, slot1 = (j1 - 1) >> 6;
            if (lane == owner1) usedmask |= 1u << slot1;
            j0 = j1; i0 = pj1;
        }

        const float Dfin = Dcum;
        #pragma unroll
        for (int c = 0; c < NSLOT; ++c) {
            if ((usedmask >> c) & 1u) {
                const float dec = Dfin - minv[c];
                vreg[c] -= dec;
                u_s[low[c] & 63] += dec;     // distinct rows -> no collision
            }
        }
        if (lane == 0) u_s[i] += Dfin;

        int jj = jfin;
        while (jj) {
            const int owner = (jj - 1) & 63, slot = (jj - 1) >> 6;
            int wv = 0;
            #pragma unroll
            for (int c = 0; c < NSLOT; ++c) if (slot == c) wv = wayreg[c];
            const int jw = __shfl(wv, owner);
            int newp;
            if (jw == 0) newp = i;
            else {
                const int ow2 = (jw - 1) & 63, sl2 = (jw - 1) >> 6;
                int pv2 = 0;
                #pragma unroll
                for (int c = 0; c < NSLOT; ++c) if (sl2 == c) pv2 = low[c] & 63;
                newp = __shfl(pv2, ow2);
            }
            if (lane == 0) p_s[jj] = newp;
            jj = jw;
        }
        // single wave: LDS deps handled by in-order waitcnt, no barrier needed
    }

    float* pred = idx_out + (size_t)mat * 2 * BS * T;   // ps (mat0) / po (mat1)
    float* tgt  = pred + BS * T;                        // ts / to
    int base = 0;
    #pragma unroll
    for (int c = 0; c < NSLOT; ++c) {
        const int q0 = c*64 + lane;
        const int pj = (q0 < Q) ? p_s[q0 + 1] : 0;
        const bool mtch = (q0 < Q) && (pj != 0);
        const unsigned long long mask = __ballot(mtch);
        if (mtch) {
            const int pos = base + __popcll(mask & ((1ull << lane) - 1ull));
            pred[b*T + pos] = (float)q0;
            tgt [b*T + pos] = (float)(pj - 1);
        }
        base += __popcll(mask);
    }
}

// ---------------------------------------------------------------------------
// Fallback path (tiny workspace): previous verified two-kernel pipeline.
// ---------------------------------------------------------------------------
__global__ __launch_bounds__(256) void cost_kernel(
    const float* __restrict__ logits_s, const float* __restrict__ logits_o,
    const float* __restrict__ boxes_s,  const float* __restrict__ boxes_o,
    const float* __restrict__ tbb_s,    const float* __restrict__ tbb_o,
    const int*   __restrict__ tids_s,   const int*   __restrict__ tids_o,
    float* __restrict__ C_s, float* __restrict__ C_o,
    float* __restrict__ blockT, int use_staged)
{
    const int w = threadIdx.x >> 6, lane = threadIdx.x & 63;
    const int rowg = blockIdx.x * 4 + w;
    const int mat = rowg / (BS * Q);
    const int r   = rowg % (BS * Q);
    const int b = r / Q, q = r % Q;

    const float* logits = mat ? logits_o : logits_s;
    const float* boxes  = mat ? boxes_o  : boxes_s;
    const float* tbb    = mat ? tbb_o    : tbb_s;
    const int*   tids   = mat ? tids_o   : tids_s;
    float* C = mat ? C_o : C_s;

    __shared__ float sprob[4][NC];
    softmax_row(logits + (size_t)r * NC, lane, sprob[w]);
    __syncthreads();

    const float4 ob = ((const float4*)boxes)[r];
    float* Crow = C + (size_t)r * MT;
    float* bT   = blockT + ((size_t)mat*BS + b) * T * Q;

    #pragma unroll
    for (int it = 0; it < 4; ++it) {
        const int t0 = it*256 + lane*4;
        const int4 cls4 = ((const int4*)tids)[t0 >> 2];
        const bool stg = use_staged && ((t0 >> 5) == b);
        vfloat4 res;
        #pragma unroll
        for (int k = 0; k < 4; ++k) {
            const int t = t0 + k;
            const float cc = -sprob[w][(&cls4.x)[k]];
            const float4 tb = ((const float4*)tbb)[t];
            const float cost = pair_cost(ob, tb, cc);
            res[k] = cost;
            if (stg) bT[(size_t)(t & 31)*Q + q] = cost;
        }
        __builtin_nontemporal_store(res, (vfloat4*)(Crow + t0));
    }
}

__global__ __launch_bounds__(64) void lsa_kernel(
    const float* __restrict__ blockT, const float* __restrict__ Cbase,
    float* __restrict__ idx_out, int use_staged)
{
    const int prob = blockIdx.x;
    const int mat = prob >> 5, b = prob & 31;
    const int lane = threadIdx.x;

    __shared__ float clds[T * Q];
    __shared__ float u_s[T + 1];
    __shared__ int   p_s[Q + 1];

    if (use_staged) {
        const float4* src = (const float4*)(blockT + (size_t)prob * T * Q);
        float4* dst = (float4*)clds;
        for (int idx = lane; idx < (T*Q)/4; idx += 64) dst[idx] = src[idx];
    } else {
        const float* cbk = Cbase + (size_t)mat*CM_SIZE + (size_t)b*Q*MT + (size_t)b*T;
        for (int t = 0; t < T; ++t)
            for (int q = lane; q < Q; q += 64)
                clds[t*Q + q] = cbk[(size_t)q * MT + t];
    }

    for (int j = lane; j <= Q; j += 64) p_s[j] = 0;
    if (lane <= T) u_s[lane] = 0.0f;
    __syncthreads();

    float vreg[NSLOT], minv[NSLOT];
    int   wayreg[NSLOT], low[NSLOT];
    #pragma unroll
    for (int c = 0; c < NSLOT; ++c) vreg[c] = 0.0f;

    for (int i = 1; i <= T; ++i) {
        #pragma unroll
        for (int c = 0; c < NSLOT; ++c) {
            const int q0 = c*64 + lane;
            minv[c] = FBIG;
            wayreg[c] = 0;
            low[c] = (q0 < Q) ? (((q0 + 1) << 6) | p_s[q0 + 1]) : 0x3FFFFF;
        }
        unsigned usedmask = 0;
        float Dcum = 0.0f;
        int j0 = 0, i0 = i, jfin;

        while (true) {
            const float u0 = u_s[i0];
            const float* crow = clds + (i0 - 1) * Q;

            float cst[NSLOT];
            #pragma unroll
            for (int c = 0; c < NSLOT; ++c) {
                const int q0 = c*64 + lane;
                cst[c] = (q0 < Q) ? crow[q0] : FBIG;
            }
            const float sh = Dcum - u0;

            unsigned long long k[NSLOT];
            #pragma unroll
            for (int c = 0; c < NSLOT; ++c) {
                const bool fre = !((usedmask >> c) & 1u);
                const float cur = (cst[c] - vreg[c]) + sh;
                const bool upd = fre && (cur < minv[c]);
                wayreg[c] = upd ? j0 : wayreg[c];
                minv[c]   = upd ? cur : minv[c];
                const float mv = fre ? minv[c] : FBIG;
                k[c] = ((unsigned long long)f32_sortable(mv) << 22) | (unsigned)low[c];
            }
            #pragma unroll
            for (int c = 0; c < 5; ++c) k[c] = (k[c+5] < k[c]) ? k[c+5] : k[c];
            k[0] = (k[3] < k[0]) ? k[3] : k[0];
            k[1] = (k[4] < k[1]) ? k[4] : k[1];
            k[0] = (k[2] < k[0]) ? k[2] : k[0];
            k[0] = (k[1] < k[0]) ? k[1] : k[0];

            unsigned long long key = wave_min_u64(k[0]);

            Dcum = f32_unsortable((unsigned)(key >> 22));
            const int j1  = (int)((key >> 6) & 0x3FF);
            const int pj1 = (int)(key & 0x3F);

            if (pj1 == 0) { jfin = j1; break; }
            const int owner1 = (j1 - 1) & 63, slot1 = (j1 - 1) >> 6;
            if (lane == owner1) usedmask |= 1u << slot1;
            j0 = j1; i0 = pj1;
        }

        const float Dfin = Dcum;
        #pragma unroll
        for (int c = 0; c < NSLOT; ++c) {
            if ((usedmask >> c) & 1u) {
                const float dec = Dfin - minv[c];
                vreg[c] -= dec;
                u_s[low[c] & 63] += dec;
            }
        }
        if (lane == 0) u_s[i] += Dfin;
        __syncthreads();

        int jj = jfin;
        while (jj) {
            const int owner = (jj - 1) & 63, slot = (jj - 1) >> 6;
            int wv = 0;
            #pragma unroll
            for (int c = 0; c < NSLOT; ++c) if (slot == c) wv = wayreg[c];
            const int jw = __shfl(wv, owner);
            int newp;
            if (jw == 0) newp = i;
            else {
                const int ow2 = (jw - 1) & 63, sl2 = (jw - 1) >> 6;
                int pv2 = 0;
                #pragma unroll
                for (int c = 0; c < NSLOT; ++c) if (sl2 == c) pv2 = low[c] & 63;
                newp = __shfl(pv2, ow2);
            }
            if (lane == 0) p_s[jj] = newp;
            jj = jw;
        }
        __syncthreads();
    }

    float* pred = idx_out + (size_t)mat * 2 * BS * T;
    float* tgt  = pred + BS * T;
    int base = 0;
    #pragma unroll
    for (int c = 0; c < NSLOT; ++c) {
        const int q0 = c*64 + lane;
        const int pj = (q0 < Q) ? p_s[q0 + 1] : 0;
        const bool mtch = (q0 < Q) && (pj != 0);
        const unsigned long long mask = __ballot(mtch);
        if (mtch) {
            const int pos = base + __popcll(mask & ((1ull << lane) - 1ull));
            pred[b*T + pos] = (float)q0;
            tgt [b*T + pos] = (float)(pj - 1);
        }
        base += __popcll(mask);
    }
}

extern "C" void kernel_launch(void* const* d_in, const int* in_sizes, int n_in,
                              void* d_out, int out_size, void* d_ws, size_t ws_size,
                              hipStream_t stream) {
    const float* logits_s = (const float*)d_in[0];
    const float* logits_o = (const float*)d_in[1];
    const float* boxes_s  = (const float*)d_in[2];
    const float* boxes_o  = (const float*)d_in[3];
    const float* tbb_s    = (const float*)d_in[4];
    const float* tbb_o    = (const float*)d_in[5];
    const int*   tids_s   = (const int*)d_in[6];
    const int*   tids_o   = (const int*)d_in[7];

    float* out = (float*)d_out;
    float* C_s = out;
    float* C_o = out + CM_SIZE;
    float* idx_out = out + 2*CM_SIZE;

    const size_t need = (size_t)NPROB * T * Q * sizeof(float);   // ~4.9 MB
    if (ws_size >= need) {
        fused_kernel<<<LSA_BLOCKS + (2*BS*Q)/4, 256, 0, stream>>>(
            logits_s, logits_o, boxes_s, boxes_o, tbb_s, tbb_o, tids_s, tids_o,
            C_s, C_o, (float*)d_ws, idx_out);
    } else {
        cost_kernel<<<(2*BS*Q)/4, 256, 0, stream>>>(logits_s, logits_o, boxes_s, boxes_o,
                                                    tbb_s, tbb_o, tids_s, tids_o,
                                                    C_s, C_o, nullptr, 0);
        lsa_kernel<<<64, 64, 0, stream>>>(nullptr, C_s, idx_out, 0);
    }
}

// Round 3
// 290.688 us; speedup vs baseline: 1.3963x; 1.3963x over previous
//
#include <hip/hip_runtime.h>
#include <math.h>

#define BS 32
#define Q  600
#define NC 152
#define T  32
#define MT (BS*T)                   // 1024 targets total
#define CM_SIZE ((size_t)BS*Q*MT)   // 19660800 elements per cost matrix
#define NSLOT 10                    // ceil(600/64)
#define FBIG 1e30f

typedef float vfloat4 __attribute__((ext_vector_type(4)));  // clang-native for nt-store

// ---------------------------------------------------------------------------
// Kernel A: build cost matrices. One WAVE per (mat,b,q) row, 4 waves/block.
// Identical to the verified 294us version except __expf (native v_exp) in
// the softmax: saves ~23 VALU ops per exp vs precise expf.
// ---------------------------------------------------------------------------
__global__ __launch_bounds__(256) void cost_kernel(
    const float* __restrict__ logits_s, const float* __restrict__ logits_o,
    const float* __restrict__ boxes_s,  const float* __restrict__ boxes_o,
    const float* __restrict__ tbb_s,    const float* __restrict__ tbb_o,
    const int*   __restrict__ tids_s,   const int*   __restrict__ tids_o,
    float* __restrict__ C_s, float* __restrict__ C_o,
    float* __restrict__ blockT, int use_staged)
{
    const int w = threadIdx.x >> 6, lane = threadIdx.x & 63;
    const int rowg = blockIdx.x * 4 + w;        // 0..38399
    const int mat = rowg / (BS * Q);
    const int r   = rowg % (BS * Q);
    const int b = r / Q, q = r % Q;

    const float* logits = mat ? logits_o : logits_s;
    const float* boxes  = mat ? boxes_o  : boxes_s;
    const float* tbb    = mat ? tbb_o    : tbb_s;
    const int*   tids   = mat ? tids_o   : tids_s;
    float* C = mat ? C_o : C_s;

    // --- softmax over NC=152 classes, wave-local ---
    const float* lrow = logits + (size_t)r * NC;
    const float l0 = (lane       < NC) ? lrow[lane]       : -INFINITY;
    const float l1 = (lane + 64  < NC) ? lrow[lane + 64]  : -INFINITY;
    const float l2 = (lane + 128 < NC) ? lrow[lane + 128] : -INFINITY;
    float m = fmaxf(l0, fmaxf(l1, l2));
    #pragma unroll
    for (int off = 32; off > 0; off >>= 1) m = fmaxf(m, __shfl_xor(m, off));
    const float e0 = __expf(l0 - m), e1 = __expf(l1 - m), e2 = __expf(l2 - m);
    float s = e0 + e1 + e2;
    #pragma unroll
    for (int off = 32; off > 0; off >>= 1) s += __shfl_xor(s, off);
    const float inv = 1.0f / s;

    __shared__ float sprob[4][NC];
    if (lane       < NC) sprob[w][lane]       = e0 * inv;
    if (lane + 64  < NC) sprob[w][lane + 64]  = e1 * inv;
    if (lane + 128 < NC) sprob[w][lane + 128] = e2 * inv;
    __syncthreads();

    const float4 ob = ((const float4*)boxes)[r];
    const float ocx = ob.x, ocy = ob.y, ow = ob.z, oh = ob.w;
    const float ox1 = ocx - 0.5f*ow, oy1 = ocy - 0.5f*oh;
    const float ox2 = ocx + 0.5f*ow, oy2 = ocy + 0.5f*oh;
    const float area1 = ow * oh;

    float* Crow = C + (size_t)r * MT;
    float* bT   = blockT + ((size_t)mat*BS + b) * T * Q;

    #pragma unroll
    for (int it = 0; it < 4; ++it) {
        const int t0 = it*256 + lane*4;
        const int4 cls4 = ((const int4*)tids)[t0 >> 2];
        // 4-aligned chunk never crosses a 32-boundary -> (t>>5) uniform over k
        const bool stg = use_staged && ((t0 >> 5) == b);
        vfloat4 res;
        #pragma unroll
        for (int k = 0; k < 4; ++k) {
            const int t = t0 + k;
            const int cls = (&cls4.x)[k];
            const float cc = -sprob[w][cls];

            const float4 tb = ((const float4*)tbb)[t];
            const float cb = fabsf(ocx-tb.x) + fabsf(ocy-tb.y)
                           + fabsf(ow -tb.z) + fabsf(oh -tb.w);

            const float tx1 = fmaf(-0.5f, tb.z, tb.x), ty1 = fmaf(-0.5f, tb.w, tb.y);
            const float tx2 = fmaf( 0.5f, tb.z, tb.x), ty2 = fmaf( 0.5f, tb.w, tb.y);
            const float area2 = tb.z * tb.w;

            const float ltx = fmaxf(ox1,tx1), lty = fmaxf(oy1,ty1);
            const float rbx = fminf(ox2,tx2), rby = fminf(oy2,ty2);
            const float iw = fmaxf(rbx-ltx, 0.0f), ih = fmaxf(rby-lty, 0.0f);
            const float inter = iw*ih;
            const float uni = area1 + area2 - inter;

            const float cx1 = fminf(ox1,tx1), cy1 = fminf(oy1,ty1);
            const float cx2 = fmaxf(ox2,tx2), cy2 = fmaxf(oy2,ty2);
            const float areac = (cx2-cx1)*(cy2-cy1);   // >= 0 by construction

            // giou = inter/uni - (areac-uni)/areac, via fast rcp (+-1 ulp)
            const float giou = inter * __builtin_amdgcn_rcpf(uni)
                             - (areac - uni) * __builtin_amdgcn_rcpf(areac);

            const float cost = cb + cc - giou;
            res[k] = cost;
            if (stg) bT[(size_t)(t & 31)*Q + q] = cost;
        }
        __builtin_nontemporal_store(res, (vfloat4*)(Crow + t0));
    }
}

// ---------------------------------------------------------------------------
// u32 DPP wave-min, result broadcast via readlane 63 (VALU pipe only).
// Half the dependent-chain length of the old u64 variant.
// ---------------------------------------------------------------------------
__device__ __forceinline__ unsigned wave_min_u32(unsigned x) {
  int v = (int)x;
  #define ST(CTRL, RMASK) { \
    int p = __builtin_amdgcn_update_dpp(v, v, CTRL, RMASK, 0xF, false); \
    v = ((unsigned)p < (unsigned)v) ? p : v; }
  ST(0xB1, 0xF)   // quad_perm [1,0,3,2]  : xor 1
  ST(0x4E, 0xF)   // quad_perm [2,3,0,1]  : xor 2
  ST(0x141, 0xF)  // row_half_mirror      : xor 4
  ST(0x140, 0xF)  // row_mirror           : xor 8
  ST(0x142, 0xA)  // row_bcast15 -> rows 1,3
  ST(0x143, 0xC)  // row_bcast31 -> rows 2,3
  #undef ST
  return (unsigned)__builtin_amdgcn_readlane(v, 63);
}

__device__ __forceinline__ unsigned f32_sortable(float f) {
  unsigned u = __float_as_uint(f);
  return u ^ ((unsigned)((int)u >> 31) | 0x80000000u);
}
__device__ __forceinline__ float f32_unsortable(unsigned s) {
  unsigned m = (unsigned)((int)(~s) >> 31) | 0x80000000u;
  return __uint_as_float(s ^ m);
}

// ---------------------------------------------------------------------------
// Kernel B: Jonker-Volgenant LSA, one wave per problem. Changes vs verified:
//  (1) cost block in LDS (kept from R1)
//  (2) column-match array p[] lives in per-lane REGISTERS (pcol) -> no p_s
//      LDS traffic on the critical path (row-start init + path rewrite)
//  (3) f32 min-tree + u32 DPP wave-min; exact smallest-column tie-break via
//      unique-winner readlane (common) or second u32 DPP-min on low (rare)
//  (4) no barriers inside the row loop (single wave, in-order DS ops)
// ---------------------------------------------------------------------------
__global__ __launch_bounds__(64) void lsa_kernel(
    const float* __restrict__ blockT, const float* __restrict__ Cbase,
    float* __restrict__ idx_out, int use_staged)
{
    const int prob = blockIdx.x;        // 0..63
    const int mat = prob >> 5, b = prob & 31;
    const int lane = threadIdx.x;

    __shared__ float clds[T * Q];       // 76.8 KB cost block, row-major [T][Q]
    __shared__ float u_s[T + 1];

    // --- stage the per-problem cost block into LDS ---
    if (use_staged) {
        const float4* src = (const float4*)(blockT + (size_t)prob * T * Q);
        float4* dst = (float4*)clds;
        for (int idx = lane; idx < (T*Q)/4; idx += 64)   // 4800 float4, 75 iters
            dst[idx] = src[idx];
    } else {
        // fallback: gather the diagonal block out of the full C matrix
        const float* cbk = Cbase + (size_t)mat*CM_SIZE + (size_t)b*Q*MT + (size_t)b*T;
        for (int t = 0; t < T; ++t)
            for (int q = lane; q < Q; q += 64)
                clds[t*Q + q] = cbk[(size_t)q * MT + t];
    }
    if (lane <= T) u_s[lane] = 0.0f;
    __syncthreads();    // once, before the row loop

    float vreg[NSLOT], minv[NSLOT];
    int   wayreg[NSLOT], low[NSLOT];
    int   pcol[NSLOT];                  // matched row of column q0 (0 = free)
    #pragma unroll
    for (int c = 0; c < NSLOT; ++c) { vreg[c] = 0.0f; pcol[c] = 0; }

    for (int i = 1; i <= T; ++i) {
        #pragma unroll
        for (int c = 0; c < NSLOT; ++c) {
            const int q0 = c*64 + lane;
            minv[c] = FBIG;
            wayreg[c] = 0;
            low[c] = (q0 < Q) ? (((q0 + 1) << 6) | pcol[c]) : 0x3FFFFF;
        }
        unsigned usedmask = 0;
        float Dcum = 0.0f;
        int j0 = 0, i0 = i, jfin;

        while (true) {
            const float u0 = u_s[i0];
            const float* crow = clds + (i0 - 1) * Q;

            float cst[NSLOT];
            #pragma unroll
            for (int c = 0; c < NSLOT; ++c) {
                const int q0 = c*64 + lane;
                cst[c] = (q0 < Q) ? crow[q0] : FBIG;
            }
            const float sh = Dcum - u0;

            float bm[NSLOT];
            #pragma unroll
            for (int c = 0; c < NSLOT; ++c) {
                const bool fre = !((usedmask >> c) & 1u);
                const float cur = (cst[c] - vreg[c]) + sh;   // verified op order
                const bool upd = fre && (cur < minv[c]);
                wayreg[c] = upd ? j0 : wayreg[c];
                minv[c]   = upd ? cur : minv[c];
                bm[c] = fre ? minv[c] : FBIG;
            }
            // per-lane f32 min tree (v_min3-friendly groupings)
            const float m0 = fminf(bm[0], fminf(bm[1], bm[2]));
            const float m1 = fminf(bm[3], fminf(bm[4], bm[5]));
            const float m2 = fminf(bm[6], fminf(bm[7], bm[8]));
            const float best = fminf(fminf(m0, m1), fminf(m2, bm[9]));
            // smallest-column winner within the lane (downward scan = exact)
            int blow = 0x3FFFFF;
            #pragma unroll
            for (int c = NSLOT - 1; c >= 0; --c) blow = (bm[c] == best) ? low[c] : blow;

            const unsigned sb = f32_sortable(best);
            const unsigned gb = wave_min_u32(sb);
            const unsigned long long mask = __ballot(sb == gb);
            int blow_w;
            if (__popcll(mask) == 1) {             // unique winner (common case)
                blow_w = __builtin_amdgcn_readlane(blow, __ffsll(mask) - 1);
            } else {                               // bitwise f32 tie (rare):
                const unsigned cand = (sb == gb) ? (unsigned)blow : 0x3FFFFFu;
                blow_w = (int)wave_min_u32(cand);  // smallest column among ties
            }

            Dcum = f32_unsortable(gb);
            const int j1  = (blow_w >> 6) & 0x3FF;
            const int pj1 = blow_w & 0x3F;

            if (pj1 == 0) { jfin = j1; break; }
            const int owner1 = (j1 - 1) & 63, slot1 = (j1 - 1) >> 6;
            if (lane == owner1) usedmask |= 1u << slot1;
            j0 = j1; i0 = pj1;
        }

        const float Dfin = Dcum;
        #pragma unroll
        for (int c = 0; c < NSLOT; ++c) {
            if ((usedmask >> c) & 1u) {
                const float dec = Dfin - minv[c];
                vreg[c] -= dec;
                u_s[low[c] & 63] += dec;     // distinct rows -> no collision
            }
        }
        if (lane == 0) u_s[i] += Dfin;

        // path rewrite, all-register (pcol). Reads use row-start p (= low&63),
        // exactly as the verified version did.
        int jj = jfin;
        while (jj) {
            const int owner = (jj - 1) & 63, slot = (jj - 1) >> 6;
            int wv = 0;
            #pragma unroll
            for (int c = 0; c < NSLOT; ++c) if (slot == c) wv = wayreg[c];
            const int jw = __shfl(wv, owner);
            int newp;
            if (jw == 0) newp = i;
            else {
                const int ow2 = (jw - 1) & 63, sl2 = (jw - 1) >> 6;
                int pv2 = 0;
                #pragma unroll
                for (int c = 0; c < NSLOT; ++c) if (sl2 == c) pv2 = low[c] & 63;
                newp = __shfl(pv2, ow2);
            }
            if (lane == owner) {
                #pragma unroll
                for (int c = 0; c < NSLOT; ++c) if (slot == c) pcol[c] = newp;
            }
            jj = jw;
        }
        // no barrier: single wave, same-type DS ops complete in order
    }

    float* pred = idx_out + (size_t)mat * 2 * BS * T;   // ps (mat0) / po (mat1)
    float* tgt  = pred + BS * T;                        // ts / to
    int base = 0;
    #pragma unroll
    for (int c = 0; c < NSLOT; ++c) {
        const int q0 = c*64 + lane;
        const int pj = (q0 < Q) ? pcol[c] : 0;
        const bool mtch = (q0 < Q) && (pj != 0);
        const unsigned long long mask = __ballot(mtch);
        if (mtch) {
            const int pos = base + __popcll(mask & ((1ull << lane) - 1ull));
            pred[b*T + pos] = (float)q0;
            tgt [b*T + pos] = (float)(pj - 1);
        }
        base += __popcll(mask);
    }
}

extern "C" void kernel_launch(void* const* d_in, const int* in_sizes, int n_in,
                              void* d_out, int out_size, void* d_ws, size_t ws_size,
                              hipStream_t stream) {
    const float* logits_s = (const float*)d_in[0];
    const float* logits_o = (const float*)d_in[1];
    const float* boxes_s  = (const float*)d_in[2];
    const float* boxes_o  = (const float*)d_in[3];
    const float* tbb_s    = (const float*)d_in[4];
    const float* tbb_o    = (const float*)d_in[5];
    const int*   tids_s   = (const int*)d_in[6];
    const int*   tids_o   = (const int*)d_in[7];

    float* out = (float*)d_out;
    float* C_s = out;
    float* C_o = out + CM_SIZE;
    float* idx_out = out + 2*CM_SIZE;

    const size_t staged_bytes = (size_t)2*BS*T*Q*sizeof(float);  // ~9.8 MB
    const int use_staged = (ws_size >= staged_bytes) ? 1 : 0;
    float* blockT = (float*)d_ws;

    cost_kernel<<<(2*BS*Q)/4, 256, 0, stream>>>(logits_s, logits_o, boxes_s, boxes_o,
                                                tbb_s, tbb_o, tids_s, tids_o,
                                                C_s, C_o, blockT, use_staged);

    lsa_kernel<<<64, 64, 0, stream>>>(blockT, C_s, idx_out, use_staged);
}

// Round 4
// 275.122 us; speedup vs baseline: 1.4753x; 1.0566x over previous
//
#include <hip/hip_runtime.h>
#include <math.h>

#define BS 32
#define Q  600
#define NC 152
#define T  32
#define MT (BS*T)                   // 1024 targets total
#define CM_SIZE ((size_t)BS*Q*MT)   // 19660800 elements per cost matrix
#define NSLOT 10                    // ceil(600/64)
#define FBIG 1e30f

typedef float vfloat4 __attribute__((ext_vector_type(4)));  // clang-native for nt-store

// ---------------------------------------------------------------------------
// Kernel A: build cost matrices. One WAVE per (mat,b,q) row, 4 waves/block.
// Byte-identical to the round-3 verified version (290.7us).
// ---------------------------------------------------------------------------
__global__ __launch_bounds__(256) void cost_kernel(
    const float* __restrict__ logits_s, const float* __restrict__ logits_o,
    const float* __restrict__ boxes_s,  const float* __restrict__ boxes_o,
    const float* __restrict__ tbb_s,    const float* __restrict__ tbb_o,
    const int*   __restrict__ tids_s,   const int*   __restrict__ tids_o,
    float* __restrict__ C_s, float* __restrict__ C_o,
    float* __restrict__ blockT, int use_staged)
{
    const int w = threadIdx.x >> 6, lane = threadIdx.x & 63;
    const int rowg = blockIdx.x * 4 + w;        // 0..38399
    const int mat = rowg / (BS * Q);
    const int r   = rowg % (BS * Q);
    const int b = r / Q, q = r % Q;

    const float* logits = mat ? logits_o : logits_s;
    const float* boxes  = mat ? boxes_o  : boxes_s;
    const float* tbb    = mat ? tbb_o    : tbb_s;
    const int*   tids   = mat ? tids_o   : tids_s;
    float* C = mat ? C_o : C_s;

    // --- softmax over NC=152 classes, wave-local ---
    const float* lrow = logits + (size_t)r * NC;
    const float l0 = (lane       < NC) ? lrow[lane]       : -INFINITY;
    const float l1 = (lane + 64  < NC) ? lrow[lane + 64]  : -INFINITY;
    const float l2 = (lane + 128 < NC) ? lrow[lane + 128] : -INFINITY;
    float m = fmaxf(l0, fmaxf(l1, l2));
    #pragma unroll
    for (int off = 32; off > 0; off >>= 1) m = fmaxf(m, __shfl_xor(m, off));
    const float e0 = __expf(l0 - m), e1 = __expf(l1 - m), e2 = __expf(l2 - m);
    float s = e0 + e1 + e2;
    #pragma unroll
    for (int off = 32; off > 0; off >>= 1) s += __shfl_xor(s, off);
    const float inv = 1.0f / s;

    __shared__ float sprob[4][NC];
    if (lane       < NC) sprob[w][lane]       = e0 * inv;
    if (lane + 64  < NC) sprob[w][lane + 64]  = e1 * inv;
    if (lane + 128 < NC) sprob[w][lane + 128] = e2 * inv;
    __syncthreads();

    const float4 ob = ((const float4*)boxes)[r];
    const float ocx = ob.x, ocy = ob.y, ow = ob.z, oh = ob.w;
    const float ox1 = ocx - 0.5f*ow, oy1 = ocy - 0.5f*oh;
    const float ox2 = ocx + 0.5f*ow, oy2 = ocy + 0.5f*oh;
    const float area1 = ow * oh;

    float* Crow = C + (size_t)r * MT;
    float* bT   = blockT + ((size_t)mat*BS + b) * T * Q;

    #pragma unroll
    for (int it = 0; it < 4; ++it) {
        const int t0 = it*256 + lane*4;
        const int4 cls4 = ((const int4*)tids)[t0 >> 2];
        // 4-aligned chunk never crosses a 32-boundary -> (t>>5) uniform over k
        const bool stg = use_staged && ((t0 >> 5) == b);
        vfloat4 res;
        #pragma unroll
        for (int k = 0; k < 4; ++k) {
            const int t = t0 + k;
            const int cls = (&cls4.x)[k];
            const float cc = -sprob[w][cls];

            const float4 tb = ((const float4*)tbb)[t];
            const float cb = fabsf(ocx-tb.x) + fabsf(ocy-tb.y)
                           + fabsf(ow -tb.z) + fabsf(oh -tb.w);

            const float tx1 = fmaf(-0.5f, tb.z, tb.x), ty1 = fmaf(-0.5f, tb.w, tb.y);
            const float tx2 = fmaf( 0.5f, tb.z, tb.x), ty2 = fmaf( 0.5f, tb.w, tb.y);
            const float area2 = tb.z * tb.w;

            const float ltx = fmaxf(ox1,tx1), lty = fmaxf(oy1,ty1);
            const float rbx = fminf(ox2,tx2), rby = fminf(oy2,ty2);
            const float iw = fmaxf(rbx-ltx, 0.0f), ih = fmaxf(rby-lty, 0.0f);
            const float inter = iw*ih;
            const float uni = area1 + area2 - inter;

            const float cx1 = fminf(ox1,tx1), cy1 = fminf(oy1,ty1);
            const float cx2 = fmaxf(ox2,tx2), cy2 = fmaxf(oy2,ty2);
            const float areac = (cx2-cx1)*(cy2-cy1);   // >= 0 by construction

            // giou = inter/uni - (areac-uni)/areac, via fast rcp (+-1 ulp)
            const float giou = inter * __builtin_amdgcn_rcpf(uni)
                             - (areac - uni) * __builtin_amdgcn_rcpf(areac);

            const float cost = cb + cc - giou;
            res[k] = cost;
            if (stg) bT[(size_t)(t & 31)*Q + q] = cost;
        }
        __builtin_nontemporal_store(res, (vfloat4*)(Crow + t0));
    }
}

// ---------------------------------------------------------------------------
// u32 DPP wave-min, result broadcast via readlane 63 (VALU pipe only).
// ---------------------------------------------------------------------------
__device__ __forceinline__ unsigned wave_min_u32(unsigned x) {
  int v = (int)x;
  #define ST(CTRL, RMASK) { \
    int p = __builtin_amdgcn_update_dpp(v, v, CTRL, RMASK, 0xF, false); \
    v = ((unsigned)p < (unsigned)v) ? p : v; }
  ST(0xB1, 0xF)   // quad_perm [1,0,3,2]  : xor 1
  ST(0x4E, 0xF)   // quad_perm [2,3,0,1]  : xor 2
  ST(0x141, 0xF)  // row_half_mirror      : xor 4
  ST(0x140, 0xF)  // row_mirror           : xor 8
  ST(0x142, 0xA)  // row_bcast15 -> rows 1,3
  ST(0x143, 0xC)  // row_bcast31 -> rows 2,3
  #undef ST
  return (unsigned)__builtin_amdgcn_readlane(v, 63);
}

__device__ __forceinline__ unsigned f32_sortable(float f) {
  unsigned u = __float_as_uint(f);
  return u ^ ((unsigned)((int)u >> 31) | 0x80000000u);
}
__device__ __forceinline__ float f32_unsortable(unsigned s) {
  unsigned m = (unsigned)((int)(~s) >> 31) | 0x80000000u;
  return __uint_as_float(s ^ m);
}

// ---------------------------------------------------------------------------
// Kernel B: JV LSA, one wave per problem. NEW vs round 3:
//  WARM START: u[i] = row minimum (dual-feasible: c-u-v >= 0 with v=0), then
//  greedy matching on tight edges (row order, smallest-index argmin col).
//  Only unmatched rows (~1-4 of 32) run the Dijkstra augmentation. Greedy
//  matched edges stay tight during augmentation because used-column updates
//  apply the coupled (u[row],v[col]) shift. Exact Hungarian => identical
//  result to reference whenever the optimum is unique (it is, robustly:
//  indices have matched across absmax~1e-2 perturbations of C all session).
// ---------------------------------------------------------------------------
__global__ __launch_bounds__(64) void lsa_kernel(
    const float* __restrict__ blockT, const float* __restrict__ Cbase,
    float* __restrict__ idx_out, int use_staged)
{
    const int prob = blockIdx.x;        // 0..63
    const int mat = prob >> 5, b = prob & 31;
    const int lane = threadIdx.x;

    __shared__ float clds[T * Q];       // 76.8 KB cost block, row-major [T][Q]
    __shared__ float u_s[T + 1];

    // --- stage the per-problem cost block into LDS ---
    if (use_staged) {
        const float4* src = (const float4*)(blockT + (size_t)prob * T * Q);
        float4* dst = (float4*)clds;
        for (int idx = lane; idx < (T*Q)/4; idx += 64)   // 4800 float4, 75 iters
            dst[idx] = src[idx];
    } else {
        const float* cbk = Cbase + (size_t)mat*CM_SIZE + (size_t)b*Q*MT + (size_t)b*T;
        for (int t = 0; t < T; ++t)
            for (int q = lane; q < Q; q += 64)
                clds[t*Q + q] = cbk[(size_t)q * MT + t];
    }
    if (lane <= T) u_s[lane] = 0.0f;
    __syncthreads();    // once, before everything

    float vreg[NSLOT], minv[NSLOT];
    int   wayreg[NSLOT], low[NSLOT];
    int   pcol[NSLOT];                  // matched row of column q0 (0 = free)
    #pragma unroll
    for (int c = 0; c < NSLOT; ++c) { vreg[c] = 0.0f; pcol[c] = 0; }

    // ================= warm start: row minima + greedy tight match =========
    unsigned um = 0;                    // bitmask of unmatched rows (bit i-1)
    for (int i = 1; i <= T; ++i) {
        const float* crow = clds + (i - 1) * Q;
        float bm[NSLOT];
        #pragma unroll
        for (int c = 0; c < NSLOT; ++c) {
            const int q0 = c*64 + lane;
            bm[c] = (q0 < Q) ? crow[q0] : FBIG;
        }
        const float m0 = fminf(bm[0], fminf(bm[1], bm[2]));
        const float m1 = fminf(bm[3], fminf(bm[4], bm[5]));
        const float m2 = fminf(bm[6], fminf(bm[7], bm[8]));
        const float best = fminf(fminf(m0, m1), fminf(m2, bm[9]));
        const unsigned gb = wave_min_u32(f32_sortable(best));
        const float gbf = f32_unsortable(gb);

        if (lane == 0) u_s[i] = gbf;    // u[i] = row min (v=0 -> feasible)

        // smallest column index attaining the row min
        int cand = 0x7FFFFFFF;
        #pragma unroll
        for (int c = NSLOT - 1; c >= 0; --c)
            cand = (bm[c] == gbf) ? (c*64 + lane) : cand;
        const int jm = (int)wave_min_u32((unsigned)cand);   // 0..599, uniform

        const int owner = jm & 63, slot = jm >> 6;
        int pv = 0;
        #pragma unroll
        for (int c = 0; c < NSLOT; ++c) if (slot == c) pv = pcol[c];
        const int cur = __shfl(pv, owner);                  // pcol[jm]
        if (cur == 0) {
            if (lane == owner) {
                #pragma unroll
                for (int c = 0; c < NSLOT; ++c) if (slot == c) pcol[c] = i;
            }
        } else {
            um |= 1u << (i - 1);        // argmin col taken -> augment later
        }
    }

    // ================= augment unmatched rows (verified machinery) =========
    for (int i = 1; i <= T; ++i) {
        if (!((um >> (i - 1)) & 1u)) continue;   // wave-uniform

        #pragma unroll
        for (int c = 0; c < NSLOT; ++c) {
            const int q0 = c*64 + lane;
            minv[c] = FBIG;
            wayreg[c] = 0;
            low[c] = (q0 < Q) ? (((q0 + 1) << 6) | pcol[c]) : 0x3FFFFF;
        }
        unsigned usedmask = 0;
        float Dcum = 0.0f;
        int j0 = 0, i0 = i, jfin;

        while (true) {
            const float u0 = u_s[i0];
            const float* crow = clds + (i0 - 1) * Q;

            float cst[NSLOT];
            #pragma unroll
            for (int c = 0; c < NSLOT; ++c) {
                const int q0 = c*64 + lane;
                cst[c] = (q0 < Q) ? crow[q0] : FBIG;
            }
            const float sh = Dcum - u0;

            float bm[NSLOT];
            #pragma unroll
            for (int c = 0; c < NSLOT; ++c) {
                const bool fre = !((usedmask >> c) & 1u);
                const float cur = (cst[c] - vreg[c]) + sh;   // verified op order
                const bool upd = fre && (cur < minv[c]);
                wayreg[c] = upd ? j0 : wayreg[c];
                minv[c]   = upd ? cur : minv[c];
                bm[c] = fre ? minv[c] : FBIG;
            }
            // per-lane f32 min tree (v_min3-friendly groupings)
            const float m0 = fminf(bm[0], fminf(bm[1], bm[2]));
            const float m1 = fminf(bm[3], fminf(bm[4], bm[5]));
            const float m2 = fminf(bm[6], fminf(bm[7], bm[8]));
            const float best = fminf(fminf(m0, m1), fminf(m2, bm[9]));
            // smallest-column winner within the lane (downward scan = exact)
            int blow = 0x3FFFFF;
            #pragma unroll
            for (int c = NSLOT - 1; c >= 0; --c) blow = (bm[c] == best) ? low[c] : blow;

            const unsigned sb = f32_sortable(best);
            const unsigned gb = wave_min_u32(sb);
            const unsigned long long mask = __ballot(sb == gb);
            int blow_w;
            if (__popcll(mask) == 1) {             // unique winner (common case)
                blow_w = __builtin_amdgcn_readlane(blow, __ffsll(mask) - 1);
            } else {                               // bitwise f32 tie (rare):
                const unsigned cand = (sb == gb) ? (unsigned)blow : 0x3FFFFFu;
                blow_w = (int)wave_min_u32(cand);  // smallest column among ties
            }

            Dcum = f32_unsortable(gb);
            const int j1  = (blow_w >> 6) & 0x3FF;
            const int pj1 = blow_w & 0x3F;

            if (pj1 == 0) { jfin = j1; break; }
            const int owner1 = (j1 - 1) & 63, slot1 = (j1 - 1) >> 6;
            if (lane == owner1) usedmask |= 1u << slot1;
            j0 = j1; i0 = pj1;
        }

        const float Dfin = Dcum;
        #pragma unroll
        for (int c = 0; c < NSLOT; ++c) {
            if ((usedmask >> c) & 1u) {
                const float dec = Dfin - minv[c];
                vreg[c] -= dec;
                u_s[low[c] & 63] += dec;     // coupled dual shift keeps matched
            }                                // edges tight (incl. greedy ones)
        }
        if (lane == 0) u_s[i] += Dfin;

        // path rewrite, all-register (pcol)
        int jj = jfin;
        while (jj) {
            const int owner = (jj - 1) & 63, slot = (jj - 1) >> 6;
            int wv = 0;
            #pragma unroll
            for (int c = 0; c < NSLOT; ++c) if (slot == c) wv = wayreg[c];
            const int jw = __shfl(wv, owner);
            int newp;
            if (jw == 0) newp = i;
            else {
                const int ow2 = (jw - 1) & 63, sl2 = (jw - 1) >> 6;
                int pv2 = 0;
                #pragma unroll
                for (int c = 0; c < NSLOT; ++c) if (sl2 == c) pv2 = low[c] & 63;
                newp = __shfl(pv2, ow2);
            }
            if (lane == owner) {
                #pragma unroll
                for (int c = 0; c < NSLOT; ++c) if (slot == c) pcol[c] = newp;
            }
            jj = jw;
        }
        // no barrier: single wave, in-order DS ops
    }

    float* pred = idx_out + (size_t)mat * 2 * BS * T;   // ps (mat0) / po (mat1)
    float* tgt  = pred + BS * T;                        // ts / to
    int base = 0;
    #pragma unroll
    for (int c = 0; c < NSLOT; ++c) {
        const int q0 = c*64 + lane;
        const int pj = (q0 < Q) ? pcol[c] : 0;
        const bool mtch = (q0 < Q) && (pj != 0);
        const unsigned long long mask = __ballot(mtch);
        if (mtch) {
            const int pos = base + __popcll(mask & ((1ull << lane) - 1ull));
            pred[b*T + pos] = (float)q0;
            tgt [b*T + pos] = (float)(pj - 1);
        }
        base += __popcll(mask);
    }
}

extern "C" void kernel_launch(void* const* d_in, const int* in_sizes, int n_in,
                              void* d_out, int out_size, void* d_ws, size_t ws_size,
                              hipStream_t stream) {
    const float* logits_s = (const float*)d_in[0];
    const float* logits_o = (const float*)d_in[1];
    const float* boxes_s  = (const float*)d_in[2];
    const float* boxes_o  = (const float*)d_in[3];
    const float* tbb_s    = (const float*)d_in[4];
    const float* tbb_o    = (const float*)d_in[5];
    const int*   tids_s   = (const int*)d_in[6];
    const int*   tids_o   = (const int*)d_in[7];

    float* out = (float*)d_out;
    float* C_s = out;
    float* C_o = out + CM_SIZE;
    float* idx_out = out + 2*CM_SIZE;

    const size_t staged_bytes = (size_t)2*BS*T*Q*sizeof(float);  // ~9.8 MB
    const int use_staged = (ws_size >= staged_bytes) ? 1 : 0;
    float* blockT = (float*)d_ws;

    cost_kernel<<<(2*BS*Q)/4, 256, 0, stream>>>(logits_s, logits_o, boxes_s, boxes_o,
                                                tbb_s, tbb_o, tids_s, tids_o,
                                                C_s, C_o, blockT, use_staged);

    lsa_kernel<<<64, 64, 0, stream>>>(blockT, C_s, idx_out, use_staged);
}

// Round 6
// 258.619 us; speedup vs baseline: 1.5695x; 1.0638x over previous
//
#include <hip/hip_runtime.h>
#include <math.h>

#define BS 32
#define Q  600
#define NC 152
#define T  32
#define MT (BS*T)                   // 1024 targets total
#define CM_SIZE ((size_t)BS*Q*MT)   // 19660800 elements per cost matrix
#define NSLOT 10                    // ceil(600/64)
#define FBIG 1e30f

typedef float vfloat4 __attribute__((ext_vector_type(4)));  // clang-native for nt-store

// ---------------------------------------------------------------------------
// Kernel A: build cost matrices. One WAVE per (mat,b,q) row, 4 waves/block.
// Identical to R4 except: blockT staging stores REMOVED (lsa now gathers its
// diagonal block straight from C). Pure C production.
// ---------------------------------------------------------------------------
__global__ __launch_bounds__(256) void cost_kernel(
    const float* __restrict__ logits_s, const float* __restrict__ logits_o,
    const float* __restrict__ boxes_s,  const float* __restrict__ boxes_o,
    const float* __restrict__ tbb_s,    const float* __restrict__ tbb_o,
    const int*   __restrict__ tids_s,   const int*   __restrict__ tids_o,
    float* __restrict__ C_s, float* __restrict__ C_o)
{
    const int w = threadIdx.x >> 6, lane = threadIdx.x & 63;
    const int rowg = blockIdx.x * 4 + w;        // 0..38399
    const int mat = rowg / (BS * Q);
    const int r   = rowg % (BS * Q);

    const float* logits = mat ? logits_o : logits_s;
    const float* boxes  = mat ? boxes_o  : boxes_s;
    const float* tbb    = mat ? tbb_o    : tbb_s;
    const int*   tids   = mat ? tids_o   : tids_s;
    float* C = mat ? C_o : C_s;

    // --- softmax over NC=152 classes, wave-local ---
    const float* lrow = logits + (size_t)r * NC;
    const float l0 = (lane       < NC) ? lrow[lane]       : -INFINITY;
    const float l1 = (lane + 64  < NC) ? lrow[lane + 64]  : -INFINITY;
    const float l2 = (lane + 128 < NC) ? lrow[lane + 128] : -INFINITY;
    float m = fmaxf(l0, fmaxf(l1, l2));
    #pragma unroll
    for (int off = 32; off > 0; off >>= 1) m = fmaxf(m, __shfl_xor(m, off));
    const float e0 = __expf(l0 - m), e1 = __expf(l1 - m), e2 = __expf(l2 - m);
    float s = e0 + e1 + e2;
    #pragma unroll
    for (int off = 32; off > 0; off >>= 1) s += __shfl_xor(s, off);
    const float inv = 1.0f / s;

    __shared__ float sprob[4][NC];
    if (lane       < NC) sprob[w][lane]       = e0 * inv;
    if (lane + 64  < NC) sprob[w][lane + 64]  = e1 * inv;
    if (lane + 128 < NC) sprob[w][lane + 128] = e2 * inv;
    __syncthreads();

    const float4 ob = ((const float4*)boxes)[r];
    const float ocx = ob.x, ocy = ob.y, ow = ob.z, oh = ob.w;
    const float ox1 = ocx - 0.5f*ow, oy1 = ocy - 0.5f*oh;
    const float ox2 = ocx + 0.5f*ow, oy2 = ocy + 0.5f*oh;
    const float area1 = ow * oh;

    float* Crow = C + (size_t)r * MT;

    #pragma unroll
    for (int it = 0; it < 4; ++it) {
        const int t0 = it*256 + lane*4;
        const int4 cls4 = ((const int4*)tids)[t0 >> 2];
        vfloat4 res;
        #pragma unroll
        for (int k = 0; k < 4; ++k) {
            const int t = t0 + k;
            const int cls = (&cls4.x)[k];
            const float cc = -sprob[w][cls];

            const float4 tb = ((const float4*)tbb)[t];
            const float cb = fabsf(ocx-tb.x) + fabsf(ocy-tb.y)
                           + fabsf(ow -tb.z) + fabsf(oh -tb.w);

            const float tx1 = fmaf(-0.5f, tb.z, tb.x), ty1 = fmaf(-0.5f, tb.w, tb.y);
            const float tx2 = fmaf( 0.5f, tb.z, tb.x), ty2 = fmaf( 0.5f, tb.w, tb.y);
            const float area2 = tb.z * tb.w;

            const float ltx = fmaxf(ox1,tx1), lty = fmaxf(oy1,ty1);
            const float rbx = fminf(ox2,tx2), rby = fminf(oy2,ty2);
            const float iw = fmaxf(rbx-ltx, 0.0f), ih = fmaxf(rby-lty, 0.0f);
            const float inter = iw*ih;
            const float uni = area1 + area2 - inter;

            const float cx1 = fminf(ox1,tx1), cy1 = fminf(oy1,ty1);
            const float cx2 = fmaxf(ox2,tx2), cy2 = fmaxf(oy2,ty2);
            const float areac = (cx2-cx1)*(cy2-cy1);   // >= 0 by construction

            // giou = inter/uni - (areac-uni)/areac, via fast rcp (+-1 ulp)
            const float giou = inter * __builtin_amdgcn_rcpf(uni)
                             - (areac - uni) * __builtin_amdgcn_rcpf(areac);

            res[k] = cb + cc - giou;
        }
        __builtin_nontemporal_store(res, (vfloat4*)(Crow + t0));
    }
}

// ---------------------------------------------------------------------------
// u32 DPP wave-min, result broadcast via readlane 63 (VALU pipe only).
// ---------------------------------------------------------------------------
__device__ __forceinline__ unsigned wave_min_u32(unsigned x) {
  int v = (int)x;
  #define ST(CTRL, RMASK) { \
    int p = __builtin_amdgcn_update_dpp(v, v, CTRL, RMASK, 0xF, false); \
    v = ((unsigned)p < (unsigned)v) ? p : v; }
  ST(0xB1, 0xF)   // quad_perm [1,0,3,2]  : xor 1
  ST(0x4E, 0xF)   // quad_perm [2,3,0,1]  : xor 2
  ST(0x141, 0xF)  // row_half_mirror      : xor 4
  ST(0x140, 0xF)  // row_mirror           : xor 8
  ST(0x142, 0xA)  // row_bcast15 -> rows 1,3
  ST(0x143, 0xC)  // row_bcast31 -> rows 2,3
  #undef ST
  return (unsigned)__builtin_amdgcn_readlane(v, 63);
}

__device__ __forceinline__ unsigned f32_sortable(float f) {
  unsigned u = __float_as_uint(f);
  return u ^ ((unsigned)((int)u >> 31) | 0x80000000u);
}
__device__ __forceinline__ float f32_unsortable(unsigned s) {
  unsigned m = (unsigned)((int)(~s) >> 31) | 0x80000000u;
  return __uint_as_float(s ^ m);
}

// ---------------------------------------------------------------------------
// Kernel B: JV LSA, one wave per problem. Identical algorithm to R4
// (row-min warm start + greedy tight match + Dijkstra augment for leftovers).
// Stages the 32x600 diagonal block DIRECTLY from C — no workspace, no
// use_staged fallback. Per lane: 8 contiguous float4 reads per q-row (the
// 32 t-values are contiguous in C's row-major layout), transposed into
// [T][Q] LDS via conflict-free ds_write_b32.
// ---------------------------------------------------------------------------
__global__ __launch_bounds__(64) void lsa_kernel(
    const float* __restrict__ Cbase, float* __restrict__ idx_out)
{
    const int prob = blockIdx.x;        // 0..63
    const int mat = prob >> 5, b = prob & 31;
    const int lane = threadIdx.x;

    __shared__ float clds[T * Q];       // 76.8 KB cost block, row-major [T][Q]
    __shared__ float u_s[T + 1];

    // --- gather the diagonal block straight out of C ---
    {
        const float* base = Cbase + (size_t)mat*CM_SIZE + (size_t)b*Q*MT + (size_t)b*T;
        for (int q = lane; q < Q; q += 64) {
            const float4* src = (const float4*)(base + (size_t)q * MT);
            float4 r[8];
            #pragma unroll
            for (int k = 0; k < 8; ++k) r[k] = src[k];
            #pragma unroll
            for (int k = 0; k < 8; ++k) {
                clds[(4*k+0)*Q + q] = r[k].x;
                clds[(4*k+1)*Q + q] = r[k].y;
                clds[(4*k+2)*Q + q] = r[k].z;
                clds[(4*k+3)*Q + q] = r[k].w;
            }
        }
    }
    if (lane <= T) u_s[lane] = 0.0f;
    __syncthreads();    // once, before everything

    float vreg[NSLOT], minv[NSLOT];
    int   wayreg[NSLOT], low[NSLOT];
    int   pcol[NSLOT];                  // matched row of column q0 (0 = free)
    #pragma unroll
    for (int c = 0; c < NSLOT; ++c) { vreg[c] = 0.0f; pcol[c] = 0; }

    // ================= warm start: row minima + greedy tight match =========
    unsigned um = 0;                    // bitmask of unmatched rows (bit i-1)
    for (int i = 1; i <= T; ++i) {
        const float* crow = clds + (i - 1) * Q;
        float bm[NSLOT];
        #pragma unroll
        for (int c = 0; c < NSLOT; ++c) {
            const int q0 = c*64 + lane;
            bm[c] = (q0 < Q) ? crow[q0] : FBIG;
        }
        const float m0 = fminf(bm[0], fminf(bm[1], bm[2]));
        const float m1 = fminf(bm[3], fminf(bm[4], bm[5]));
        const float m2 = fminf(bm[6], fminf(bm[7], bm[8]));
        const float best = fminf(fminf(m0, m1), fminf(m2, bm[9]));
        const unsigned gb = wave_min_u32(f32_sortable(best));
        const float gbf = f32_unsortable(gb);

        if (lane == 0) u_s[i] = gbf;    // u[i] = row min (v=0 -> feasible)

        // smallest column index attaining the row min
        int cand = 0x7FFFFFFF;
        #pragma unroll
        for (int c = NSLOT - 1; c >= 0; --c)
            cand = (bm[c] == gbf) ? (c*64 + lane) : cand;
        const int jm = (int)wave_min_u32((unsigned)cand);   // 0..599, uniform

        const int owner = jm & 63, slot = jm >> 6;
        int pv = 0;
        #pragma unroll
        for (int c = 0; c < NSLOT; ++c) if (slot == c) pv = pcol[c];
        const int cur = __shfl(pv, owner);                  // pcol[jm]
        if (cur == 0) {
            if (lane == owner) {
                #pragma unroll
                for (int c = 0; c < NSLOT; ++c) if (slot == c) pcol[c] = i;
            }
        } else {
            um |= 1u << (i - 1);        // argmin col taken -> augment later
        }
    }

    // ================= augment unmatched rows (verified machinery) =========
    for (int i = 1; i <= T; ++i) {
        if (!((um >> (i - 1)) & 1u)) continue;   // wave-uniform

        #pragma unroll
        for (int c = 0; c < NSLOT; ++c) {
            const int q0 = c*64 + lane;
            minv[c] = FBIG;
            wayreg[c] = 0;
            low[c] = (q0 < Q) ? (((q0 + 1) << 6) | pcol[c]) : 0x3FFFFF;
        }
        unsigned usedmask = 0;
        float Dcum = 0.0f;
        int j0 = 0, i0 = i, jfin;

        while (true) {
            const float u0 = u_s[i0];
            const float* crow = clds + (i0 - 1) * Q;

            float cst[NSLOT];
            #pragma unroll
            for (int c = 0; c < NSLOT; ++c) {
                const int q0 = c*64 + lane;
                cst[c] = (q0 < Q) ? crow[q0] : FBIG;
            }
            const float sh = Dcum - u0;

            float bm[NSLOT];
            #pragma unroll
            for (int c = 0; c < NSLOT; ++c) {
                const bool fre = !((usedmask >> c) & 1u);
                const float cur = (cst[c] - vreg[c]) + sh;   // verified op order
                const bool upd = fre && (cur < minv[c]);
                wayreg[c] = upd ? j0 : wayreg[c];
                minv[c]   = upd ? cur : minv[c];
                bm[c] = fre ? minv[c] : FBIG;
            }
            // per-lane f32 min tree (v_min3-friendly groupings)
            const float m0 = fminf(bm[0], fminf(bm[1], bm[2]));
            const float m1 = fminf(bm[3], fminf(bm[4], bm[5]));
            const float m2 = fminf(bm[6], fminf(bm[7], bm[8]));
            const float best = fminf(fminf(m0, m1), fminf(m2, bm[9]));
            // smallest-column winner within the lane (downward scan = exact)
            int blow = 0x3FFFFF;
            #pragma unroll
            for (int c = NSLOT - 1; c >= 0; --c) blow = (bm[c] == best) ? low[c] : blow;

            const unsigned sb = f32_sortable(best);
            const unsigned gb = wave_min_u32(sb);
            const unsigned long long mask = __ballot(sb == gb);
            int blow_w;
            if (__popcll(mask) == 1) {             // unique winner (common case)
                blow_w = __builtin_amdgcn_readlane(blow, __ffsll(mask) - 1);
            } else {                               // bitwise f32 tie (rare):
                const unsigned cand = (sb == gb) ? (unsigned)blow : 0x3FFFFFu;
                blow_w = (int)wave_min_u32(cand);  // smallest column among ties
            }

            Dcum = f32_unsortable(gb);
            const int j1  = (blow_w >> 6) & 0x3FF;
            const int pj1 = blow_w & 0x3F;

            if (pj1 == 0) { jfin = j1; break; }
            const int owner1 = (j1 - 1) & 63, slot1 = (j1 - 1) >> 6;
            if (lane == owner1) usedmask |= 1u << slot1;
            j0 = j1; i0 = pj1;
        }

        const float Dfin = Dcum;
        #pragma unroll
        for (int c = 0; c < NSLOT; ++c) {
            if ((usedmask >> c) & 1u) {
                const float dec = Dfin - minv[c];
                vreg[c] -= dec;
                u_s[low[c] & 63] += dec;     // coupled dual shift keeps matched
            }                                // edges tight (incl. greedy ones)
        }
        if (lane == 0) u_s[i] += Dfin;

        // path rewrite, all-register (pcol)
        int jj = jfin;
        while (jj) {
            const int owner = (jj - 1) & 63, slot = (jj - 1) >> 6;
            int wv = 0;
            #pragma unroll
            for (int c = 0; c < NSLOT; ++c) if (slot == c) wv = wayreg[c];
            const int jw = __shfl(wv, owner);
            int newp;
            if (jw == 0) newp = i;
            else {
                const int ow2 = (jw - 1) & 63, sl2 = (jw - 1) >> 6;
                int pv2 = 0;
                #pragma unroll
                for (int c = 0; c < NSLOT; ++c) if (sl2 == c) pv2 = low[c] & 63;
                newp = __shfl(pv2, ow2);
            }
            if (lane == owner) {
                #pragma unroll
                for (int c = 0; c < NSLOT; ++c) if (slot == c) pcol[c] = newp;
            }
            jj = jw;
        }
        // no barrier: single wave, in-order DS ops
    }

    float* pred = idx_out + (size_t)mat * 2 * BS * T;   // ps (mat0) / po (mat1)
    float* tgt  = pred + BS * T;                        // ts / to
    int base = 0;
    #pragma unroll
    for (int c = 0; c < NSLOT; ++c) {
        const int q0 = c*64 + lane;
        const int pj = (q0 < Q) ? pcol[c] : 0;
        const bool mtch = (q0 < Q) && (pj != 0);
        const unsigned long long mask = __ballot(mtch);
        if (mtch) {
            const int pos = base + __popcll(mask & ((1ull << lane) - 1ull));
            pred[b*T + pos] = (float)q0;
            tgt [b*T + pos] = (float)(pj - 1);
        }
        base += __popcll(mask);
    }
}

extern "C" void kernel_launch(void* const* d_in, const int* in_sizes, int n_in,
                              void* d_out, int out_size, void* d_ws, size_t ws_size,
                              hipStream_t stream) {
    const float* logits_s = (const float*)d_in[0];
    const float* logits_o = (const float*)d_in[1];
    const float* boxes_s  = (const float*)d_in[2];
    const float* boxes_o  = (const float*)d_in[3];
    const float* tbb_s    = (const float*)d_in[4];
    const float* tbb_o    = (const float*)d_in[5];
    const int*   tids_s   = (const int*)d_in[6];
    const int*   tids_o   = (const int*)d_in[7];

    float* out = (float*)d_out;
    float* C_s = out;
    float* C_o = out + CM_SIZE;
    float* idx_out = out + 2*CM_SIZE;

    cost_kernel<<<(2*BS*Q)/4, 256, 0, stream>>>(logits_s, logits_o, boxes_s, boxes_o,
                                                tbb_s, tbb_o, tids_s, tids_o,
                                                C_s, C_o);

    lsa_kernel<<<64, 64, 0, stream>>>(C_s, idx_out);
}

// Round 7
// 245.319 us; speedup vs baseline: 1.6546x; 1.0542x over previous
//
#include <hip/hip_runtime.h>
#include <math.h>

#define BS 32
#define Q  600
#define NC 152
#define T  32
#define MT (BS*T)                   // 1024 targets total
#define CM_SIZE ((size_t)BS*Q*MT)   // 19660800 elements per cost matrix
#define NSLOT 10                    // ceil(600/64)
#define FBIG 1e30f

typedef float vfloat4 __attribute__((ext_vector_type(4)));  // clang-native for nt-store

// ---------------------------------------------------------------------------
// Kernel A: build cost matrices. One WAVE per (mat,b,q) row, 4 waves/block.
// Identical to R6 except single-rcp GIoU:
//   inter/uni - (areac-uni)/areac == [inter*areac - (areac-uni)*uni]/(uni*areac)
// halves transcendental-pipe ops (2 rcp -> 1 rcp per pair).
// ---------------------------------------------------------------------------
__global__ __launch_bounds__(256) void cost_kernel(
    const float* __restrict__ logits_s, const float* __restrict__ logits_o,
    const float* __restrict__ boxes_s,  const float* __restrict__ boxes_o,
    const float* __restrict__ tbb_s,    const float* __restrict__ tbb_o,
    const int*   __restrict__ tids_s,   const int*   __restrict__ tids_o,
    float* __restrict__ C_s, float* __restrict__ C_o)
{
    const int w = threadIdx.x >> 6, lane = threadIdx.x & 63;
    const int rowg = blockIdx.x * 4 + w;        // 0..38399
    const int mat = rowg / (BS * Q);
    const int r   = rowg % (BS * Q);

    const float* logits = mat ? logits_o : logits_s;
    const float* boxes  = mat ? boxes_o  : boxes_s;
    const float* tbb    = mat ? tbb_o    : tbb_s;
    const int*   tids   = mat ? tids_o   : tids_s;
    float* C = mat ? C_o : C_s;

    // --- softmax over NC=152 classes, wave-local ---
    const float* lrow = logits + (size_t)r * NC;
    const float l0 = (lane       < NC) ? lrow[lane]       : -INFINITY;
    const float l1 = (lane + 64  < NC) ? lrow[lane + 64]  : -INFINITY;
    const float l2 = (lane + 128 < NC) ? lrow[lane + 128] : -INFINITY;
    float m = fmaxf(l0, fmaxf(l1, l2));
    #pragma unroll
    for (int off = 32; off > 0; off >>= 1) m = fmaxf(m, __shfl_xor(m, off));
    const float e0 = __expf(l0 - m), e1 = __expf(l1 - m), e2 = __expf(l2 - m);
    float s = e0 + e1 + e2;
    #pragma unroll
    for (int off = 32; off > 0; off >>= 1) s += __shfl_xor(s, off);
    const float inv = 1.0f / s;

    __shared__ float sprob[4][NC];
    if (lane       < NC) sprob[w][lane]       = e0 * inv;
    if (lane + 64  < NC) sprob[w][lane + 64]  = e1 * inv;
    if (lane + 128 < NC) sprob[w][lane + 128] = e2 * inv;
    __syncthreads();

    const float4 ob = ((const float4*)boxes)[r];
    const float ocx = ob.x, ocy = ob.y, ow = ob.z, oh = ob.w;
    const float ox1 = ocx - 0.5f*ow, oy1 = ocy - 0.5f*oh;
    const float ox2 = ocx + 0.5f*ow, oy2 = ocy + 0.5f*oh;
    const float area1 = ow * oh;

    float* Crow = C + (size_t)r * MT;

    #pragma unroll
    for (int it = 0; it < 4; ++it) {
        const int t0 = it*256 + lane*4;
        const int4 cls4 = ((const int4*)tids)[t0 >> 2];
        vfloat4 res;
        #pragma unroll
        for (int k = 0; k < 4; ++k) {
            const int t = t0 + k;
            const int cls = (&cls4.x)[k];
            const float cc = -sprob[w][cls];

            const float4 tb = ((const float4*)tbb)[t];
            const float cb = fabsf(ocx-tb.x) + fabsf(ocy-tb.y)
                           + fabsf(ow -tb.z) + fabsf(oh -tb.w);

            const float tx1 = fmaf(-0.5f, tb.z, tb.x), ty1 = fmaf(-0.5f, tb.w, tb.y);
            const float tx2 = fmaf( 0.5f, tb.z, tb.x), ty2 = fmaf( 0.5f, tb.w, tb.y);
            const float area2 = tb.z * tb.w;

            const float ltx = fmaxf(ox1,tx1), lty = fmaxf(oy1,ty1);
            const float rbx = fminf(ox2,tx2), rby = fminf(oy2,ty2);
            const float iw = fmaxf(rbx-ltx, 0.0f), ih = fmaxf(rby-lty, 0.0f);
            const float inter = iw*ih;
            const float uni = area1 + area2 - inter;

            const float cx1 = fminf(ox1,tx1), cy1 = fminf(oy1,ty1);
            const float cx2 = fmaxf(ox2,tx2), cy2 = fmaxf(oy2,ty2);
            const float areac = (cx2-cx1)*(cy2-cy1);   // >= 0 by construction

            // single-rcp giou (boxes in [0,1]^2: products O(1), no overflow)
            const float num  = inter*areac - (areac - uni)*uni;
            const float giou = num * __builtin_amdgcn_rcpf(uni * areac);

            res[k] = cb + cc - giou;
        }
        __builtin_nontemporal_store(res, (vfloat4*)(Crow + t0));
    }
}

// ---------------------------------------------------------------------------
// u32 DPP wave-min, result broadcast via readlane 63 (VALU pipe only).
// ---------------------------------------------------------------------------
__device__ __forceinline__ unsigned wave_min_u32(unsigned x) {
  int v = (int)x;
  #define ST(CTRL, RMASK) { \
    int p = __builtin_amdgcn_update_dpp(v, v, CTRL, RMASK, 0xF, false); \
    v = ((unsigned)p < (unsigned)v) ? p : v; }
  ST(0xB1, 0xF)   // quad_perm [1,0,3,2]  : xor 1
  ST(0x4E, 0xF)   // quad_perm [2,3,0,1]  : xor 2
  ST(0x141, 0xF)  // row_half_mirror      : xor 4
  ST(0x140, 0xF)  // row_mirror           : xor 8
  ST(0x142, 0xA)  // row_bcast15 -> rows 1,3
  ST(0x143, 0xC)  // row_bcast31 -> rows 2,3
  #undef ST
  return (unsigned)__builtin_amdgcn_readlane(v, 63);
}

__device__ __forceinline__ unsigned f32_sortable(float f) {
  unsigned u = __float_as_uint(f);
  return u ^ ((unsigned)((int)u >> 31) | 0x80000000u);
}
__device__ __forceinline__ float f32_unsortable(unsigned s) {
  unsigned m = (unsigned)((int)(~s) >> 31) | 0x80000000u;
  return __uint_as_float(s ^ m);
}

// ---------------------------------------------------------------------------
// Kernel B: JV LSA. NEW vs R6: 256 threads (4 waves).
//   Phase 1: all 4 waves gather the 32x600 block from C into LDS (4x fewer
//            strided-load rounds than 1-wave).
//   Phase 2: row-(min, argmin-col) for the 32 rows computed 8-per-wave in
//            PARALLEL (depends only on clds, not matching state — decisions
//            bit-identical to R6's serial scan). Results -> u_s[] / rjm_s[].
//   Phase 3: wave 0 alone: greedy tight match (reads precomputed argmins),
//            then Dijkstra augments — machinery byte-identical to R6.
// ---------------------------------------------------------------------------
__global__ __launch_bounds__(256) void lsa_kernel(
    const float* __restrict__ Cbase, float* __restrict__ idx_out)
{
    const int prob = blockIdx.x;        // 0..63
    const int mat = prob >> 5, b = prob & 31;
    const int tid = threadIdx.x, w = tid >> 6, lane = tid & 63;

    __shared__ float clds[T * Q];       // 76.8 KB cost block, row-major [T][Q]
    __shared__ float u_s[T + 1];
    __shared__ int   rjm_s[T + 1];      // per-row smallest argmin column

    // --- phase 1: gather the diagonal block straight out of C (4 waves) ---
    {
        const float* base = Cbase + (size_t)mat*CM_SIZE + (size_t)b*Q*MT + (size_t)b*T;
        for (int q = tid; q < Q; q += 256) {
            const float4* src = (const float4*)(base + (size_t)q * MT);
            float4 r[8];
            #pragma unroll
            for (int k = 0; k < 8; ++k) r[k] = src[k];
            #pragma unroll
            for (int k = 0; k < 8; ++k) {
                clds[(4*k+0)*Q + q] = r[k].x;
                clds[(4*k+1)*Q + q] = r[k].y;
                clds[(4*k+2)*Q + q] = r[k].z;
                clds[(4*k+3)*Q + q] = r[k].w;
            }
        }
    }
    if (tid == 0) u_s[0] = 0.0f;
    __syncthreads();

    // --- phase 2: parallel row minima + argmin columns (8 rows per wave) ---
    for (int i = w*8 + 1; i <= w*8 + 8; ++i) {
        const float* crow = clds + (i - 1) * Q;
        float bm[NSLOT];
        #pragma unroll
        for (int c = 0; c < NSLOT; ++c) {
            const int q0 = c*64 + lane;
            bm[c] = (q0 < Q) ? crow[q0] : FBIG;
        }
        const float m0 = fminf(bm[0], fminf(bm[1], bm[2]));
        const float m1 = fminf(bm[3], fminf(bm[4], bm[5]));
        const float m2 = fminf(bm[6], fminf(bm[7], bm[8]));
        const float best = fminf(fminf(m0, m1), fminf(m2, bm[9]));
        const unsigned gb = wave_min_u32(f32_sortable(best));
        const float gbf = f32_unsortable(gb);

        // smallest column index attaining the row min (same scan as R6)
        int cand = 0x7FFFFFFF;
        #pragma unroll
        for (int c = NSLOT - 1; c >= 0; --c)
            cand = (bm[c] == gbf) ? (c*64 + lane) : cand;
        const int jm = (int)wave_min_u32((unsigned)cand);   // 0..599, uniform

        if (lane == 0) { u_s[i] = gbf; rjm_s[i] = jm; }     // u[i] = row min
    }
    __syncthreads();
    if (w != 0) return;                 // wave 0 carries on alone

    float vreg[NSLOT], minv[NSLOT];
    int   wayreg[NSLOT], low[NSLOT];
    int   pcol[NSLOT];                  // matched row of column q0 (0 = free)
    #pragma unroll
    for (int c = 0; c < NSLOT; ++c) { vreg[c] = 0.0f; pcol[c] = 0; }

    // --- phase 3a: greedy tight match on precomputed argmins ---
    unsigned um = 0;                    // bitmask of unmatched rows (bit i-1)
    for (int i = 1; i <= T; ++i) {
        const int jm = rjm_s[i];
        const int owner = jm & 63, slot = jm >> 6;
        int pv = 0;
        #pragma unroll
        for (int c = 0; c < NSLOT; ++c) if (slot == c) pv = pcol[c];
        const int cur = __shfl(pv, owner);                  // pcol[jm]
        if (cur == 0) {
            if (lane == owner) {
                #pragma unroll
                for (int c = 0; c < NSLOT; ++c) if (slot == c) pcol[c] = i;
            }
        } else {
            um |= 1u << (i - 1);        // argmin col taken -> augment later
        }
    }

    // --- phase 3b: augment unmatched rows (verified machinery, unchanged) ---
    for (int i = 1; i <= T; ++i) {
        if (!((um >> (i - 1)) & 1u)) continue;   // wave-uniform

        #pragma unroll
        for (int c = 0; c < NSLOT; ++c) {
            const int q0 = c*64 + lane;
            minv[c] = FBIG;
            wayreg[c] = 0;
            low[c] = (q0 < Q) ? (((q0 + 1) << 6) | pcol[c]) : 0x3FFFFF;
        }
        unsigned usedmask = 0;
        float Dcum = 0.0f;
        int j0 = 0, i0 = i, jfin;

        while (true) {
            const float u0 = u_s[i0];
            const float* crow = clds + (i0 - 1) * Q;

            float cst[NSLOT];
            #pragma unroll
            for (int c = 0; c < NSLOT; ++c) {
                const int q0 = c*64 + lane;
                cst[c] = (q0 < Q) ? crow[q0] : FBIG;
            }
            const float sh = Dcum - u0;

            float bm[NSLOT];
            #pragma unroll
            for (int c = 0; c < NSLOT; ++c) {
                const bool fre = !((usedmask >> c) & 1u);
                const float cur = (cst[c] - vreg[c]) + sh;   // verified op order
                const bool upd = fre && (cur < minv[c]);
                wayreg[c] = upd ? j0 : wayreg[c];
                minv[c]   = upd ? cur : minv[c];
                bm[c] = fre ? minv[c] : FBIG;
            }
            // per-lane f32 min tree (v_min3-friendly groupings)
            const float m0 = fminf(bm[0], fminf(bm[1], bm[2]));
            const float m1 = fminf(bm[3], fminf(bm[4], bm[5]));
            const float m2 = fminf(bm[6], fminf(bm[7], bm[8]));
            const float best = fminf(fminf(m0, m1), fminf(m2, bm[9]));
            // smallest-column winner within the lane (downward scan = exact)
            int blow = 0x3FFFFF;
            #pragma unroll
            for (int c = NSLOT - 1; c >= 0; --c) blow = (bm[c] == best) ? low[c] : blow;

            const unsigned sb = f32_sortable(best);
            const unsigned gb = wave_min_u32(sb);
            const unsigned long long mask = __ballot(sb == gb);
            int blow_w;
            if (__popcll(mask) == 1) {             // unique winner (common case)
                blow_w = __builtin_amdgcn_readlane(blow, __ffsll(mask) - 1);
            } else {                               // bitwise f32 tie (rare):
                const unsigned cand = (sb == gb) ? (unsigned)blow : 0x3FFFFFu;
                blow_w = (int)wave_min_u32(cand);  // smallest column among ties
            }

            Dcum = f32_unsortable(gb);
            const int j1  = (blow_w >> 6) & 0x3FF;
            const int pj1 = blow_w & 0x3F;

            if (pj1 == 0) { jfin = j1; break; }
            const int owner1 = (j1 - 1) & 63, slot1 = (j1 - 1) >> 6;
            if (lane == owner1) usedmask |= 1u << slot1;
            j0 = j1; i0 = pj1;
        }

        const float Dfin = Dcum;
        #pragma unroll
        for (int c = 0; c < NSLOT; ++c) {
            if ((usedmask >> c) & 1u) {
                const float dec = Dfin - minv[c];
                vreg[c] -= dec;
                u_s[low[c] & 63] += dec;     // coupled dual shift keeps matched
            }                                // edges tight (incl. greedy ones)
        }
        if (lane == 0) u_s[i] += Dfin;

        // path rewrite, all-register (pcol)
        int jj = jfin;
        while (jj) {
            const int owner = (jj - 1) & 63, slot = (jj - 1) >> 6;
            int wv = 0;
            #pragma unroll
            for (int c = 0; c < NSLOT; ++c) if (slot == c) wv = wayreg[c];
            const int jw = __shfl(wv, owner);
            int newp;
            if (jw == 0) newp = i;
            else {
                const int ow2 = (jw - 1) & 63, sl2 = (jw - 1) >> 6;
                int pv2 = 0;
                #pragma unroll
                for (int c = 0; c < NSLOT; ++c) if (sl2 == c) pv2 = low[c] & 63;
                newp = __shfl(pv2, ow2);
            }
            if (lane == owner) {
                #pragma unroll
                for (int c = 0; c < NSLOT; ++c) if (slot == c) pcol[c] = newp;
            }
            jj = jw;
        }
        // no barrier: single wave, in-order DS ops
    }

    float* pred = idx_out + (size_t)mat * 2 * BS * T;   // ps (mat0) / po (mat1)
    float* tgt  = pred + BS * T;                        // ts / to
    int base = 0;
    #pragma unroll
    for (int c = 0; c < NSLOT; ++c) {
        const int q0 = c*64 + lane;
        const int pj = (q0 < Q) ? pcol[c] : 0;
        const bool mtch = (q0 < Q) && (pj != 0);
        const unsigned long long mask = __ballot(mtch);
        if (mtch) {
            const int pos = base + __popcll(mask & ((1ull << lane) - 1ull));
            pred[b*T + pos] = (float)q0;
            tgt [b*T + pos] = (float)(pj - 1);
        }
        base += __popcll(mask);
    }
}

extern "C" void kernel_launch(void* const* d_in, const int* in_sizes, int n_in,
                              void* d_out, int out_size, void* d_ws, size_t ws_size,
                              hipStream_t stream) {
    const float* logits_s = (const float*)d_in[0];
    const float* logits_o = (const float*)d_in[1];
    const float* boxes_s  = (const float*)d_in[2];
    const float* boxes_o  = (const float*)d_in[3];
    const float* tbb_s    = (const float*)d_in[4];
    const float* tbb_o    = (const float*)d_in[5];
    const int*   tids_s   = (const int*)d_in[6];
    const int*   tids_o   = (const int*)d_in[7];

    float* out = (float*)d_out;
    float* C_s = out;
    float* C_o = out + CM_SIZE;
    float* idx_out = out + 2*CM_SIZE;

    cost_kernel<<<(2*BS*Q)/4, 256, 0, stream>>>(logits_s, logits_o, boxes_s, boxes_o,
                                                tbb_s, tbb_o, tids_s, tids_o,
                                                C_s, C_o);

    lsa_kernel<<<64, 256, 0, stream>>>(C_s, idx_out);
}